// Round 1
// baseline (367.532 us; speedup 1.0000x reference)
//
#include <hip/hip_runtime.h>

// Problem constants
#define B_   4
#define C_   256
#define N_   4096   // H*W
#define D_   32     // qk dim
#define TJ   64     // K/V tile (j) size
#define SVP  72     // padded row stride (halves) for s_v / s_p (64 + 8)
#define SKP  40     // padded row stride (halves) for s_k (32 + 8)

typedef _Float16 half8  __attribute__((ext_vector_type(8)));
typedef _Float16 half4t __attribute__((ext_vector_type(4)));
typedef float    f32x4  __attribute__((ext_vector_type(4)));

// ---------------------------------------------------------------------------
// Kernel 1: projections.  q = Wq@sem + bq, k = Wk@str + bk, v = Wv@str + bv
// A-operand = W (m=o, k=c: rows contiguous), B-operand = X (n=pixel).
// Outputs: Qh,Kh (B,N,32) f16;  Vh (B,C,N) f16 (transposed for flash V-frags).
// ---------------------------------------------------------------------------
__global__ __launch_bounds__(256) void proj_kernel(
    const float* __restrict__ sem, const float* __restrict__ str,
    const float* __restrict__ Wq,  const float* __restrict__ bq,
    const float* __restrict__ Wk,  const float* __restrict__ bk,
    const float* __restrict__ Wv,  const float* __restrict__ bv,
    _Float16* __restrict__ Qh, _Float16* __restrict__ Kh, _Float16* __restrict__ Vh)
{
    const int bid  = blockIdx.x;
    const int b    = bid >> 6;
    const int n0   = (bid & 63) << 6;           // 64-pixel tile
    const int tid  = threadIdx.x;
    const int w    = tid >> 6;                  // wave 0..3; wave w owns o-tiles w*5..w*5+4
    const int lane = tid & 63;
    const int quad = lane >> 4;
    const int l15  = lane & 15;

    f32x4 acc[5][4];
    #pragma unroll
    for (int i = 0; i < 5; ++i)
        #pragma unroll
        for (int j = 0; j < 4; ++j) { acc[i][j][0]=0.f; acc[i][j][1]=0.f; acc[i][j][2]=0.f; acc[i][j][3]=0.f; }

    const size_t xbase = (size_t)b * C_ * N_;

    #pragma unroll 1
    for (int kc = 0; kc < 8; ++kc) {            // 8 k-chunks of 32 channels
        const int c0 = kc*32 + quad*8;
        half8 bs[4] = {}, bt[4];
        #pragma unroll
        for (int nt = 0; nt < 4; ++nt) {        // B-frags from structural (all waves)
            const int n = n0 + nt*16 + l15;
            const float* pt = str + xbase + (size_t)c0 * N_ + n;
            #pragma unroll
            for (int j = 0; j < 8; ++j) bt[nt][j] = (_Float16)pt[(size_t)j * N_];
        }
        if (w == 0) {                           // only wave0 owns q-tiles -> needs semantic
            #pragma unroll
            for (int nt = 0; nt < 4; ++nt) {
                const int n = n0 + nt*16 + l15;
                const float* ps = sem + xbase + (size_t)c0 * N_ + n;
                #pragma unroll
                for (int j = 0; j < 8; ++j) bs[nt][j] = (_Float16)ps[(size_t)j * N_];
            }
        }
        #pragma unroll
        for (int mi = 0; mi < 5; ++mi) {
            const int t = w*5 + mi;             // o-tile id: 0,1=q  2,3=k  4..19=v
            const float* wr;
            if (t < 2)      wr = Wq + (size_t)(t*16       + l15) * C_;
            else if (t < 4) wr = Wk + (size_t)((t-2)*16   + l15) * C_;
            else            wr = Wv + (size_t)((t-4)*16   + l15) * C_;
            f32x4 w0 = *(const f32x4*)(wr + c0);
            f32x4 w1 = *(const f32x4*)(wr + c0 + 4);
            half8 af;
            af[0]=(_Float16)w0[0]; af[1]=(_Float16)w0[1]; af[2]=(_Float16)w0[2]; af[3]=(_Float16)w0[3];
            af[4]=(_Float16)w1[0]; af[5]=(_Float16)w1[1]; af[6]=(_Float16)w1[2]; af[7]=(_Float16)w1[3];
            #pragma unroll
            for (int nt = 0; nt < 4; ++nt)
                acc[mi][nt] = __builtin_amdgcn_mfma_f32_16x16x32_f16(
                                  af, (t < 2) ? bs[nt] : bt[nt], acc[mi][nt], 0, 0, 0);
        }
    }

    // Epilogue: bias add, f16 convert, store.
    #pragma unroll
    for (int mi = 0; mi < 5; ++mi) {
        const int t = w*5 + mi;
        if (t < 4) {
            const bool isq = (t < 2);
            const int  tt  = isq ? t : (t - 2);
            f32x4 b4 = *(const f32x4*)((isq ? bq : bk) + tt*16 + quad*4);
            _Float16* dst = isq ? Qh : Kh;
            #pragma unroll
            for (int nt = 0; nt < 4; ++nt) {
                const int n = n0 + nt*16 + l15;
                f32x4 a = acc[mi][nt];
                half4t h;
                h[0]=(_Float16)(a[0]+b4[0]); h[1]=(_Float16)(a[1]+b4[1]);
                h[2]=(_Float16)(a[2]+b4[2]); h[3]=(_Float16)(a[3]+b4[3]);
                *(half4t*)(dst + ((size_t)(b*N_ + n))*D_ + tt*16 + quad*4) = h;
            }
        } else {
            const int o0 = (t-4)*16 + quad*4;   // C/D layout: row(o) = quad*4 + reg
            f32x4 b4 = *(const f32x4*)(bv + o0);
            #pragma unroll
            for (int nt = 0; nt < 4; ++nt) {
                const int n = n0 + nt*16 + l15;
                f32x4 a = acc[mi][nt];
                _Float16* vv = Vh + ((size_t)b*C_ + o0)*N_ + n;   // (B,C,N), lanes contiguous in n
                vv[0]            = (_Float16)(a[0]+b4[0]);
                vv[(size_t)N_]   = (_Float16)(a[1]+b4[1]);
                vv[(size_t)2*N_] = (_Float16)(a[2]+b4[2]);
                vv[(size_t)3*N_] = (_Float16)(a[3]+b4[3]);
            }
        }
    }
}

// ---------------------------------------------------------------------------
// Kernel 2: flash attention + gamma*out + semantic.
// Block = (b, 64 q-rows). 4 waves: wave w computes S/softmax for its 16-row
// m-tile, but accumulates O for ALL 64 rows on its own 64-channel c-slice
// (cuts LDS V re-reads 4x). P transposes C-layout -> A-layout through LDS.
// ---------------------------------------------------------------------------
__global__ __launch_bounds__(256) void flash_kernel(
    const _Float16* __restrict__ Qh, const _Float16* __restrict__ Kh,
    const _Float16* __restrict__ Vh, const float* __restrict__ sem,
    const float* __restrict__ gma, float* __restrict__ out)
{
    __shared__ __align__(16) _Float16 s_k[64 * SKP];   //  5 KB, K tile [j][d]
    __shared__ __align__(16) _Float16 s_p[64 * SVP];   //  9 KB, P tile [i][j]
    __shared__ float s_al[64];
    __shared__ float s_l[64];
    __shared__ __align__(16) _Float16 s_v[256 * SVP];  // 36 KB, V tile [c][j]; epilogue scratch after loop

    const int bid  = blockIdx.x;
    const int b    = bid >> 6;
    const int n0   = (bid & 63) << 6;
    const int tid  = threadIdx.x;
    const int w    = tid >> 6;
    const int lane = tid & 63;
    const int quad = lane >> 4;
    const int l15  = lane & 15;

    // Q A-frag for this wave's m-tile: A[m=lane&15][k=quad*8+j]
    const half8 qf = *(const half8*)(Qh + ((size_t)(b*N_ + n0 + w*16 + l15))*D_ + quad*8);

    f32x4 oacc[16];                              // [mt][ct]: 64 rows x 64-ch slice
    #pragma unroll
    for (int i = 0; i < 16; ++i) { oacc[i][0]=0.f; oacc[i][1]=0.f; oacc[i][2]=0.f; oacc[i][3]=0.f; }
    float m_run[4] = {-1e30f,-1e30f,-1e30f,-1e30f};
    float l_run[4] = {0.f,0.f,0.f,0.f};

    const _Float16* kbase = Kh + (size_t)b*N_*D_;
    const _Float16* vbase = Vh + (size_t)b*C_*N_;

    #pragma unroll 1
    for (int jb = 0; jb < N_/TJ; ++jb) {
        const int j0 = jb * TJ;
        __syncthreads();                          // prev iter's PV done -> safe to restage
        {   // stage K tile (64x32 halves), padded rows
            const int r = tid >> 2, part = tid & 3;
            *(uint4*)(s_k + r*SKP + part*8) = *(const uint4*)(kbase + (size_t)(j0 + r)*D_ + part*8);
        }
        #pragma unroll
        for (int i = 0; i < 8; ++i) {             // stage V tile (256x64 halves), padded rows
            const int q8 = tid + i*256;
            const int c = q8 >> 3, part = q8 & 7;
            *(uint4*)(s_v + c*SVP + part*8) = *(const uint4*)(vbase + (size_t)c*N_ + j0 + part*8);
        }
        __syncthreads();

        // S = Q K^T for this wave's 16 rows (4 j-subtiles)
        f32x4 sf[4];
        #pragma unroll
        for (int js = 0; js < 4; ++js) {
            half8 kf = *(const half8*)(s_k + (js*16 + l15)*SKP + quad*8);
            f32x4 z; z[0]=0.f; z[1]=0.f; z[2]=0.f; z[3]=0.f;
            sf[js] = __builtin_amdgcn_mfma_f32_16x16x32_f16(qf, kf, z, 0, 0, 0);
        }
        // online softmax (C-layout: row = quad*4+r, col = js*16 + lane&15)
        float al[4];
        #pragma unroll
        for (int r = 0; r < 4; ++r) {
            float mx = fmaxf(fmaxf(sf[0][r], sf[1][r]), fmaxf(sf[2][r], sf[3][r]));
            mx = fmaxf(mx, __shfl_xor(mx, 1));
            mx = fmaxf(mx, __shfl_xor(mx, 2));
            mx = fmaxf(mx, __shfl_xor(mx, 4));
            mx = fmaxf(mx, __shfl_xor(mx, 8));
            const float mn = fmaxf(m_run[r], mx);
            const float a  = __expf(m_run[r] - mn);
            const float p0 = __expf(sf[0][r]-mn), p1 = __expf(sf[1][r]-mn);
            const float p2 = __expf(sf[2][r]-mn), p3 = __expf(sf[3][r]-mn);
            float rs = (p0+p1) + (p2+p3);
            rs += __shfl_xor(rs, 1); rs += __shfl_xor(rs, 2);
            rs += __shfl_xor(rs, 4); rs += __shfl_xor(rs, 8);
            m_run[r] = mn;  l_run[r] = l_run[r]*a + rs;  al[r] = a;
            const int prow = (w*16 + quad*4 + r) * SVP;
            s_p[prow +  0 + l15] = (_Float16)p0;
            s_p[prow + 16 + l15] = (_Float16)p1;
            s_p[prow + 32 + l15] = (_Float16)p2;
            s_p[prow + 48 + l15] = (_Float16)p3;
        }
        if (l15 == 0) {
            #pragma unroll
            for (int r = 0; r < 4; ++r) s_al[w*16 + quad*4 + r] = al[r];
        }
        __syncthreads();                          // P + alpha visible to all waves

        // rescale O (all 64 rows) by alpha
        #pragma unroll
        for (int mt = 0; mt < 4; ++mt) {
            f32x4 a4 = *(const f32x4*)(s_al + mt*16 + quad*4);
            #pragma unroll
            for (int ct = 0; ct < 4; ++ct) {
                oacc[mt*4+ct][0] *= a4[0]; oacc[mt*4+ct][1] *= a4[1];
                oacc[mt*4+ct][2] *= a4[2]; oacc[mt*4+ct][3] *= a4[3];
            }
        }
        // O += P V  (wave's c-slice = [w*64, w*64+64))
        #pragma unroll
        for (int kc = 0; kc < 2; ++kc) {
            half8 pf[4];
            #pragma unroll
            for (int mt = 0; mt < 4; ++mt)
                pf[mt] = *(const half8*)(s_p + (mt*16 + l15)*SVP + kc*32 + quad*8);
            #pragma unroll
            for (int ct = 0; ct < 4; ++ct) {
                half8 vf = *(const half8*)(s_v + (w*64 + ct*16 + l15)*SVP + kc*32 + quad*8);
                #pragma unroll
                for (int mt = 0; mt < 4; ++mt)
                    oacc[mt*4+ct] = __builtin_amdgcn_mfma_f32_16x16x32_f16(pf[mt], vf, oacc[mt*4+ct], 0, 0, 0);
            }
        }
    }

    if (l15 == 0) {
        #pragma unroll
        for (int r = 0; r < 4; ++r) s_l[w*16 + quad*4 + r] = l_run[r];
    }
    __syncthreads();                              // l visible; all s_v reads done (reuse as s_e)

    const float g = gma[0];
    float* s_e = ((float*)s_v) + w*1280;          // per-wave 64c x 16i (pad 20) fp32 scratch

    #pragma unroll 1
    for (int mt = 0; mt < 4; ++mt) {
        f32x4 lf = *(const f32x4*)(s_l + mt*16 + quad*4);
        #pragma unroll
        for (int ct = 0; ct < 4; ++ct) {
            f32x4 o = oacc[mt*4+ct];
            f32x4 v;
            v[0] = g*o[0]/lf[0]; v[1] = g*o[1]/lf[1];
            v[2] = g*o[2]/lf[2]; v[3] = g*o[3]/lf[3];
            *(f32x4*)(s_e + (ct*16 + l15)*20 + quad*4) = v;   // [c_local][i_local]
        }
        #pragma unroll
        for (int cc = 0; cc < 16; ++cc) {         // coalesced store: lanes contiguous in i
            const float  val = s_e[(cc*4 + quad)*20 + l15];
            const int    c   = w*64 + cc*4 + quad;
            const int    i   = n0 + mt*16 + l15;
            const size_t idx = ((size_t)(b*C_ + c))*N_ + i;
            out[idx] = val + sem[idx];
        }
    }
}

extern "C" void kernel_launch(void* const* d_in, const int* in_sizes, int n_in,
                              void* d_out, int out_size, void* d_ws, size_t ws_size,
                              hipStream_t stream) {
    const float* sem = (const float*)d_in[0];
    const float* str = (const float*)d_in[1];
    const float* Wq  = (const float*)d_in[2];
    const float* bq  = (const float*)d_in[3];
    const float* Wk  = (const float*)d_in[4];
    const float* bk  = (const float*)d_in[5];
    const float* Wv  = (const float*)d_in[6];
    const float* bv  = (const float*)d_in[7];
    const float* gma = (const float*)d_in[8];
    float* out = (float*)d_out;

    // Workspace layout (f16): Qh 1MB | Kh 1MB | Vh 8MB  (total 10MB)
    _Float16* Qh = (_Float16*)d_ws;
    _Float16* Kh = Qh + (size_t)B_*N_*D_;
    _Float16* Vh = Kh + (size_t)B_*N_*D_;

    hipLaunchKernelGGL(proj_kernel, dim3(B_*(N_/64)), dim3(256), 0, stream,
                       sem, str, Wq, bq, Wk, bk, Wv, bv, Qh, Kh, Vh);
    hipLaunchKernelGGL(flash_kernel, dim3(B_*(N_/64)), dim3(256), 0, stream,
                       Qh, Kh, Vh, sem, gma, out);
}

// Round 2
// 275.587 us; speedup vs baseline: 1.3336x; 1.3336x over previous
//
#include <hip/hip_runtime.h>

// Problem constants
#define B_   4
#define C_   256
#define N_   4096   // H*W
#define D_   32     // qk projection dim
#define TJ   64     // K/V tile (j) size
#define SKP  40     // s_k row stride (halves): 32 + 8   (16B-aligned rows)
#define SVP  72     // s_v row stride (halves): 64 + 8
#define SPP  72     // s_p row stride (halves): 64 + 8
#define CXP  130    // proj s_x paired-row stride (halves): 128 + 2

typedef _Float16 half8  __attribute__((ext_vector_type(8)));
typedef _Float16 half4t __attribute__((ext_vector_type(4)));
typedef _Float16 half2v __attribute__((ext_vector_type(2)));
typedef float    f32x4  __attribute__((ext_vector_type(4)));

union FragU { uint u[4]; half8 h; };

// ---------------------------------------------------------------------------
// Kernel 1: projections. 20 o-tiles of 16 (q:0-1, k:2-3, v:4-19) split over
// 2 blocks (h) x 4 waves. X staged via coalesced float4 -> LDS f16 in a
// channel-paired layout so B-frags are 4 conflict-free b32 reads.
// Outputs: Qh,Kh in (B, 4 dchunk, N, 8) f16; Vh in (B, C, N) f16.
// ---------------------------------------------------------------------------
__global__ __launch_bounds__(256, 2) void proj_kernel(
    const float* __restrict__ sem, const float* __restrict__ str,
    const float* __restrict__ Wq,  const float* __restrict__ bq,
    const float* __restrict__ Wk,  const float* __restrict__ bk,
    const float* __restrict__ Wv,  const float* __restrict__ bv,
    _Float16* __restrict__ Qh, _Float16* __restrict__ Kh, _Float16* __restrict__ Vh)
{
    __shared__ _Float16 s_xt[16 * CXP];   // structural chunk (32c paired -> 16 rows)
    __shared__ _Float16 s_xs[16 * CXP];   // semantic chunk (h==0 only)

    const int bid = blockIdx.x;
    const int h   = bid & 1;              // o-tile half
    const int nt6 = (bid >> 1) & 63;      // pixel tile
    const int b   = bid >> 7;
    const int n0  = nt6 * 64;
    const int tid = threadIdx.x;
    const int w    = tid >> 6;
    const int lane = tid & 63;
    const int quad = lane >> 4;
    const int l15  = lane & 15;

    const int cnt = (w < 2) ? 3 : 2;                       // tiles per wave: 3,3,2,2
    const int t0  = h*10 + ((w < 2) ? w*3 : 6 + (w-2)*2);  // first global tile id
    const bool need_sem = (h == 0);

    f32x4 acc[3][4];
    #pragma unroll
    for (int i = 0; i < 3; ++i)
        #pragma unroll
        for (int j = 0; j < 4; ++j) { acc[i][j][0]=0.f; acc[i][j][1]=0.f; acc[i][j][2]=0.f; acc[i][j][3]=0.f; }

    // staging map: thread loads float4 at (c = p*16 + sc, n = n0 + sn .. +3)
    const int sc = tid >> 4;        // 0..15
    const int sn = (tid & 15) * 4;  // 0..60
    const size_t xbase = (size_t)b * C_ * N_;

    float4 xt[2], xs[2];
    #pragma unroll
    for (int p = 0; p < 2; ++p)
        xt[p] = *(const float4*)(str + xbase + (size_t)(p*16 + sc) * N_ + n0 + sn);
    if (need_sem)
        #pragma unroll
        for (int p = 0; p < 2; ++p)
            xs[p] = *(const float4*)(sem + xbase + (size_t)(p*16 + sc) * N_ + n0 + sn);

    #pragma unroll 1
    for (int kc = 0; kc < 8; ++kc) {
        __syncthreads();
        // write staged chunk: half index = c2*CXP + n*2 + (c&1)
        #pragma unroll
        for (int p = 0; p < 2; ++p) {
            const int c  = p*16 + sc;
            const int c2 = c >> 1, cb = c & 1;
            #pragma unroll
            for (int t = 0; t < 4; ++t)
                s_xt[c2*CXP + (sn + t)*2 + cb] = (_Float16)xt[p][t];
            if (need_sem)
                #pragma unroll
                for (int t = 0; t < 4; ++t)
                    s_xs[c2*CXP + (sn + t)*2 + cb] = (_Float16)xs[p][t];
        }
        __syncthreads();
        if (kc < 7) {   // prefetch next chunk while computing
            #pragma unroll
            for (int p = 0; p < 2; ++p)
                xt[p] = *(const float4*)(str + xbase + (size_t)((kc+1)*32 + p*16 + sc) * N_ + n0 + sn);
            if (need_sem)
                #pragma unroll
                for (int p = 0; p < 2; ++p)
                    xs[p] = *(const float4*)(sem + xbase + (size_t)((kc+1)*32 + p*16 + sc) * N_ + n0 + sn);
        }

        // B-frags: lane l15 = n, element pair v -> c2 = quad*4+v  (conflict-free b32)
        half8 bt[4], bs_[4];
        #pragma unroll
        for (int nt = 0; nt < 4; ++nt) {
            FragU fu;
            #pragma unroll
            for (int v = 0; v < 4; ++v)
                fu.u[v] = *(const uint*)(s_xt + (quad*4 + v)*CXP + (nt*16 + l15)*2);
            bt[nt] = fu.h;
        }
        if (w == 0 && h == 0) {
            #pragma unroll
            for (int nt = 0; nt < 4; ++nt) {
                FragU fu;
                #pragma unroll
                for (int v = 0; v < 4; ++v)
                    fu.u[v] = *(const uint*)(s_xs + (quad*4 + v)*CXP + (nt*16 + l15)*2);
                bs_[nt] = fu.h;
            }
        }

        #pragma unroll
        for (int mi = 0; mi < 3; ++mi) {
            if (mi >= cnt) break;
            const int t = t0 + mi;
            const float* wr;
            if (t < 2)      wr = Wq + (size_t)(t*16     + l15) * C_;
            else if (t < 4) wr = Wk + (size_t)((t-2)*16 + l15) * C_;
            else            wr = Wv + (size_t)((t-4)*16 + l15) * C_;
            f32x4 w0v = *(const f32x4*)(wr + kc*32 + quad*8);
            f32x4 w1v = *(const f32x4*)(wr + kc*32 + quad*8 + 4);
            half8 af;
            af[0]=(_Float16)w0v[0]; af[1]=(_Float16)w0v[1]; af[2]=(_Float16)w0v[2]; af[3]=(_Float16)w0v[3];
            af[4]=(_Float16)w1v[0]; af[5]=(_Float16)w1v[1]; af[6]=(_Float16)w1v[2]; af[7]=(_Float16)w1v[3];
            #pragma unroll
            for (int nt = 0; nt < 4; ++nt)
                acc[mi][nt] = __builtin_amdgcn_mfma_f32_16x16x32_f16(
                                  af, (t < 2) ? bs_[nt] : bt[nt], acc[mi][nt], 0, 0, 0);
        }
    }

    // Epilogue
    #pragma unroll
    for (int mi = 0; mi < 3; ++mi) {
        if (mi >= cnt) break;
        const int t = t0 + mi;
        if (t < 4) {
            const bool isq = (t < 2);
            const int  tt  = isq ? t : (t - 2);
            f32x4 b4 = *(const f32x4*)((isq ? bq : bk) + tt*16 + quad*4);
            _Float16* dst = isq ? Qh : Kh;
            const int dc  = tt*2 + (quad >> 1);       // d-chunk
            const int off = (quad & 1) * 4;           // within-chunk offset
            #pragma unroll
            for (int nt = 0; nt < 4; ++nt) {
                const int n = n0 + nt*16 + l15;
                f32x4 a = acc[mi][nt];
                half4t hq;
                hq[0]=(_Float16)(a[0]+b4[0]); hq[1]=(_Float16)(a[1]+b4[1]);
                hq[2]=(_Float16)(a[2]+b4[2]); hq[3]=(_Float16)(a[3]+b4[3]);
                *(half4t*)(dst + ((size_t)(b*4 + dc) * N_ + n) * 8 + off) = hq;
            }
        } else {
            const int o0 = (t-4)*16 + quad*4;
            f32x4 b4 = *(const f32x4*)(bv + o0);
            #pragma unroll
            for (int nt = 0; nt < 4; ++nt) {
                const int n = n0 + nt*16 + l15;
                f32x4 a = acc[mi][nt];
                _Float16* vv = Vh + ((size_t)(b*C_) + o0) * (size_t)N_ + n;
                vv[0]            = (_Float16)(a[0]+b4[0]);
                vv[(size_t)N_]   = (_Float16)(a[1]+b4[1]);
                vv[(size_t)2*N_] = (_Float16)(a[2]+b4[2]);
                vv[(size_t)3*N_] = (_Float16)(a[3]+b4[3]);
            }
        }
    }
}

// ---------------------------------------------------------------------------
// Kernel 2: flash attention (S^T formulation) + gamma*out + semantic.
// Grid = B x 64 qtiles x 2 c-halves (512 blocks -> 2/CU). Wave w owns 16
// q-rows (lane l15 = row) and all 128 c of the block's half. S^T = mfma(K,Q)
// puts per-row softmax state in per-lane scalars; P round-trips through
// per-wave-private LDS (no barrier); O accumulates as D[c][i] -> direct
// coalesced store. K/V tiles prefetched into regs across the barrier.
// ---------------------------------------------------------------------------
__global__ __launch_bounds__(256, 2) void flash_kernel(
    const _Float16* __restrict__ Qh, const _Float16* __restrict__ Kh,
    const _Float16* __restrict__ Vh, const float* __restrict__ sem,
    const float* __restrict__ gma, float* __restrict__ out)
{
    __shared__ __align__(16) _Float16 s_k[64 * SKP];     //  5 KB  [j][d]
    __shared__ __align__(16) _Float16 s_v[128 * SVP];    // 18 KB  [c_local][j]
    __shared__ __align__(16) _Float16 s_p[4 * 16 * SPP]; //  9 KB  per-wave [i][j]

    const int bid = blockIdx.x;
    const int h   = bid & 1;
    const int qt  = (bid >> 1) & 63;
    const int b   = bid >> 7;
    const int n0  = qt * 64;
    const int c0  = h * 128;
    const int tid = threadIdx.x;
    const int w    = tid >> 6;
    const int lane = tid & 63;
    const int quad = lane >> 4;
    const int l15  = lane & 15;
    const int i_row = n0 + w*16 + l15;       // this lane's q row

    // Q B-frag: B[k=d][n=i], lane l15 = i, d-chunk = quad
    const half8 qf = *(const half8*)(Qh + ((size_t)(b*4 + quad) * N_ + i_row) * 8);

    f32x4 acc[8];
    #pragma unroll
    for (int i = 0; i < 8; ++i) { acc[i][0]=0.f; acc[i][1]=0.f; acc[i][2]=0.f; acc[i][3]=0.f; }
    float m_run = -3e38f, l_run = 0.f;

    // staging addresses
    const _Float16* ksrc = Kh + ((size_t)(b*4 + w) * N_ + lane) * 8;         // wave w loads d-chunk w, row j=lane
    const int vrow  = tid >> 3;   // 0..31
    const int vpart = tid & 7;
    const _Float16* vsrc = Vh + ((size_t)(b*C_) + c0 + vrow) * (size_t)N_ + vpart*8;
    _Float16* kdst = s_k + lane*SKP + w*8;
    _Float16* vdst = s_v + vrow*SVP + vpart*8;
    _Float16* prow = s_p + (w*16 + l15) * SPP;

    uint4 kreg = *(const uint4*)(ksrc);
    uint4 vreg[4];
    #pragma unroll
    for (int t = 0; t < 4; ++t) vreg[t] = *(const uint4*)(vsrc + (size_t)t*32*N_);

    #pragma unroll 1
    for (int jb = 0; jb < N_/TJ; ++jb) {
        __syncthreads();                         // prev iter's LDS reads complete
        *(uint4*)kdst = kreg;
        #pragma unroll
        for (int t = 0; t < 4; ++t) *(uint4*)(vdst + t*32*SVP) = vreg[t];
        __syncthreads();
        if (jb < N_/TJ - 1) {                    // prefetch next tile (in flight during compute)
            const int joff = (jb + 1) * TJ;
            kreg = *(const uint4*)(ksrc + (size_t)joff * 8);
            #pragma unroll
            for (int t = 0; t < 4; ++t)
                vreg[t] = *(const uint4*)(vsrc + (size_t)t*32*N_ + joff);
        }

        // S^T: D[m=j][n=i] = sum_d K[j][d] Q[i][d]
        f32x4 sf[4];
        #pragma unroll
        for (int js = 0; js < 4; ++js) {
            half8 kf = *(const half8*)(s_k + (js*16 + l15)*SKP + quad*8);
            f32x4 z; z[0]=0.f; z[1]=0.f; z[2]=0.f; z[3]=0.f;
            sf[js] = __builtin_amdgcn_mfma_f32_16x16x32_f16(kf, qf, z, 0, 0, 0);
        }

        // online softmax: lane owns row i, 16 j-values in regs; reduce across quads
        float mx = sf[0][0];
        #pragma unroll
        for (int js = 0; js < 4; ++js)
            #pragma unroll
            for (int r = 0; r < 4; ++r) mx = fmaxf(mx, sf[js][r]);
        mx = fmaxf(mx, __shfl_xor(mx, 16));
        mx = fmaxf(mx, __shfl_xor(mx, 32));
        const float mn = fmaxf(m_run, mx);
        const float a  = __expf(m_run - mn);
        float p[4][4], rs = 0.f;
        #pragma unroll
        for (int js = 0; js < 4; ++js)
            #pragma unroll
            for (int r = 0; r < 4; ++r) { p[js][r] = __expf(sf[js][r] - mn); rs += p[js][r]; }
        rs += __shfl_xor(rs, 16);
        rs += __shfl_xor(rs, 32);
        m_run = mn;
        l_run = l_run * a + rs;

        // write P to per-wave LDS: P[i][j], j = js*16 + quad*4 + {0..3}
        #pragma unroll
        for (int js = 0; js < 4; ++js)
            #pragma unroll
            for (int rp = 0; rp < 2; ++rp) {
                half2v hp; hp[0] = (_Float16)p[js][2*rp]; hp[1] = (_Float16)p[js][2*rp+1];
                *(half2v*)(prow + js*16 + quad*4 + 2*rp) = hp;
            }

        // rescale O by alpha (per-lane scalar)
        #pragma unroll
        for (int ct = 0; ct < 8; ++ct) {
            acc[ct][0] *= a; acc[ct][1] *= a; acc[ct][2] *= a; acc[ct][3] *= a;
        }

        // O[c][i] += sum_j V[c][j] P[i][j]
        #pragma unroll
        for (int kc = 0; kc < 2; ++kc) {
            half8 pf = *(const half8*)(prow + kc*32 + quad*8);
            #pragma unroll
            for (int ct = 0; ct < 8; ++ct) {
                half8 vf = *(const half8*)(s_v + (ct*16 + l15)*SVP + kc*32 + quad*8);
                acc[ct] = __builtin_amdgcn_mfma_f32_16x16x32_f16(vf, pf, acc[ct], 0, 0, 0);
            }
        }
    }

    // Epilogue: O^T layout D[c][i] stores directly coalesced (lanes contiguous in i)
    const float scale = gma[0] / l_run;
    #pragma unroll
    for (int ct = 0; ct < 8; ++ct) {
        #pragma unroll
        for (int r = 0; r < 4; ++r) {
            const int c = c0 + ct*16 + quad*4 + r;
            const size_t idx = ((size_t)(b*C_ + c)) * N_ + i_row;
            out[idx] = acc[ct][r] * scale + sem[idx];
        }
    }
}

extern "C" void kernel_launch(void* const* d_in, const int* in_sizes, int n_in,
                              void* d_out, int out_size, void* d_ws, size_t ws_size,
                              hipStream_t stream) {
    const float* sem = (const float*)d_in[0];
    const float* str = (const float*)d_in[1];
    const float* Wq  = (const float*)d_in[2];
    const float* bq  = (const float*)d_in[3];
    const float* Wk  = (const float*)d_in[4];
    const float* bk  = (const float*)d_in[5];
    const float* Wv  = (const float*)d_in[6];
    const float* bv  = (const float*)d_in[7];
    const float* gma = (const float*)d_in[8];
    float* out = (float*)d_out;

    // Workspace (f16): Qh 1MB | Kh 1MB | Vh 8MB
    _Float16* Qh = (_Float16*)d_ws;
    _Float16* Kh = Qh + (size_t)B_*N_*D_;
    _Float16* Vh = Kh + (size_t)B_*N_*D_;

    hipLaunchKernelGGL(proj_kernel, dim3(B_*(N_/64)*2), dim3(256), 0, stream,
                       sem, str, Wq, bq, Wk, bk, Wv, bv, Qh, Kh, Vh);
    hipLaunchKernelGGL(flash_kernel, dim3(B_*(N_/64)*2), dim3(256), 0, stream,
                       Qh, Kh, Vh, sem, gma, out);
}